// Round 1
// baseline (89.613 us; speedup 1.0000x reference)
//
#include <hip/hip_runtime.h>

// RenderingModel: scatter-add of 64x64 filters at N particle positions onto a
// 512x512 canvas (cropped). Gather formulation: each block owns a 32x32 output
// tile AND a 1024-particle segment (grid.z = 8). Phase 1 compacts hits into
// LDS; phase 2 accumulates in registers; epilogue combines segments with
// global fp32 atomicAdd (d_out zeroed via hipMemsetAsync).
//
// R4 -> R5: phase 2 was VALU-issue-bound on the validity chain (~37 VALU per
// hit-thread, of which 12 were cmp/cndmask/select and 7 were clamp setup).
// New scheme: build a ZERO-BORDERED padded filter table in d_ws (per part
// 66x66, filter at [1..64][1..64], border rows/cols zero, 4.46 MB total —
// workspace is 256 MB per the harness poison fill). Clamping an index into
// [-1,64] now lands on a zero element, so the clamped load IS the correct
// value: all v_cmp/v_cndmask deleted, address math halved (~21 VALU per
// hit-thread). Accumulation order unchanged -> bitwise-identical output.
// Runtime guard: if ws_size < pad table, fall back to the R4 select body.

#define H_  512
#define W_  512
#define FH_ 64
#define FW_ 64
#define TILE_ 32
#define THREADS_ 256
#define SEG_LEN_ 1024   // particles per segment; LDS list sized to this
#define NPARTS_  256
#define PADD_    66                         // 64 + 1 zero border each side
#define PAD_ELEMS_ (PADD_ * PADD_)          // 4356 floats per part
#define PAD_BYTES_ ((size_t)NPARTS_ * PAD_ELEMS_ * sizeof(float))  // ~4.46 MB

__device__ __forceinline__ int clamp63(int v) {
    return min(max(v, 0), 63);   // -> v_med3_i32
}
__device__ __forceinline__ int clamp65(int v) {
    return min(max(v, 0), 65);   // -> v_med3_i32 (index into 66-wide pad)
}

// One block per part: write the 66x66 zero-bordered copy of its 64x64 filter.
__global__ __launch_bounds__(256)
void build_pad_kernel(const float* __restrict__ filters, float* __restrict__ pad) {
    const int p = blockIdx.x;
    const float* __restrict__ src = filters + (p << 12);   // 64*64 = 4096
    float* __restrict__ dst = pad + p * PAD_ELEMS_;
    for (int idx = threadIdx.x; idx < PAD_ELEMS_; idx += 256) {
        const int r  = idx / PADD_;
        const int c  = idx - r * PADD_;
        const int fr = r - 1, fc = c - 1;
        float v = 0.f;
        if ((unsigned)fr < (unsigned)FH_ && (unsigned)fc < (unsigned)FW_)
            v = src[(fr << 6) + fc];
        dst[idx] = v;
    }
}

template<bool PADDED>
__global__ __launch_bounds__(THREADS_, 8)
void render_tile_kernel(const int* __restrict__ phw,
                        const float* __restrict__ filt,   // padded table if PADDED, else raw filters
                        float* __restrict__ out, int n) {
    __shared__ unsigned int s_list[SEG_LEN_];
    __shared__ int s_cnt;

    const int t   = threadIdx.x;
    const int tx0 = blockIdx.x * TILE_;
    const int ty0 = blockIdx.y * TILE_;
    const int k0  = blockIdx.z * SEG_LEN_;
    const int k1  = (k0 + SEG_LEN_ < n) ? (k0 + SEG_LEN_) : n;

    if (t == 0) s_cnt = 0;
    __syncthreads();

    // ---- Phase 1: bbox test + compaction of this segment into LDS ----
    for (int k = k0 + t; k < k1; k += THREADS_) {
        const int part = phw[k * 3 + 0];
        const int row  = phw[k * 3 + 1];
        const int col  = phw[k * 3 + 2];
        const bool hit =
            (row >= ty0 - (FH_ / 2 - 1)) && (row <= ty0 + TILE_ - 1 + FH_ / 2) &&
            (col >= tx0 - (FW_ / 2 - 1)) && (col <= tx0 + TILE_ - 1 + FW_ / 2);
        if (hit) {
            const int idx = atomicAdd(&s_cnt, 1);
            // pack: part(8b) | row(9b) | col(9b)
            s_list[idx] = ((unsigned)part << 18) | ((unsigned)row << 9) | (unsigned)col;
        }
    }
    __syncthreads();
    const int cnt = s_cnt;

    // ---- Phase 2: accumulate owned pixels in registers ----
    // Thread t owns pixels (x = tx0 + (t&31), y = ty0 + (t>>5) + 8q), q=0..3.
    const int xl    = t & 31;
    const int yb    = t >> 5;          // 0..7
    const int x     = tx0 + xl;
    const int ybase = ty0 + yb;
    // Padded-path bases: +FW/2(+FH/2) filter-origin shift plus +1 border offset.
    const int xp33  = x + (FW_ / 2) + 1;
    const int yp33  = ybase + (FH_ / 2) + 1;

    float acc0 = 0.f, acc1 = 0.f, acc2 = 0.f, acc3 = 0.f;

    // One hit's contribution. Entries are wave-uniform -> readfirstlane puts
    // part/row/col in SGPRs; loads are SGPR-base + small vector offset.
    auto body = [&](unsigned v) {
        const int part = (int)__builtin_amdgcn_readfirstlane(v >> 18);
        const int row  = (int)__builtin_amdgcn_readfirstlane((v >> 9) & 511u);
        const int col  = (int)__builtin_amdgcn_readfirstlane(v & 511u);

        if constexpr (PADDED) {
            // Branchless AND select-free: clamped index lands on a zero border,
            // so the loaded value is already correct (0 outside the filter).
            const float* __restrict__ f = filt + part * PAD_ELEMS_;  // SGPR base
            const int jc = clamp65(xp33 - col);    // col index into pad, [0,65]
            const int i1 = yp33 - row;             // row index (+1 border), [-30,71]
            acc0 += f[clamp65(i1     ) * PADD_ + jc];
            acc1 += f[clamp65(i1 +  8) * PADD_ + jc];
            acc2 += f[clamp65(i1 + 16) * PADD_ + jc];
            acc3 += f[clamp65(i1 + 24) * PADD_ + jc];
        } else {
            // R4 fallback: branchless clamped loads + value selects.
            const float* __restrict__ f = filt + (part << 12);  // SGPR base
            const int  j   = x - col + (FW_ / 2);
            const int  jc  = clamp63(j);
            const bool jok = (unsigned)j < (unsigned)FW_;
            const int  i0  = ybase - row + (FH_ / 2);
            const int ia = i0;      const int ib = i0 + 8;
            const int ic = i0 + 16; const int id = i0 + 24;
            const float va = f[clamp63(ia) * FW_ + jc];
            const float vb = f[clamp63(ib) * FW_ + jc];
            const float vc = f[clamp63(ic) * FW_ + jc];
            const float vd = f[clamp63(id) * FW_ + jc];
            acc0 += (jok && (unsigned)ia < (unsigned)FH_) ? va : 0.f;
            acc1 += (jok && (unsigned)ib < (unsigned)FH_) ? vb : 0.f;
            acc2 += (jok && (unsigned)ic < (unsigned)FH_) ? vc : 0.f;
            acc3 += (jok && (unsigned)id < (unsigned)FH_) ? vd : 0.f;
        }
    };

    int k = 0;
    for (; k + 4 <= cnt; k += 4) {
        // 4 wave-uniform entries in one 16B LDS read (k%4==0 -> aligned)
        const uint4 vv = *(const uint4*)&s_list[k];
        body(vv.x); body(vv.y); body(vv.z); body(vv.w);
    }
    for (; k < cnt; ++k) body(s_list[k]);

    // ---- Epilogue: combine segments via device-scope fp32 atomics ----
    atomicAdd(&out[(ybase +  0) * W_ + x], acc0);
    atomicAdd(&out[(ybase +  8) * W_ + x], acc1);
    atomicAdd(&out[(ybase + 16) * W_ + x], acc2);
    atomicAdd(&out[(ybase + 24) * W_ + x], acc3);
}

extern "C" void kernel_launch(void* const* d_in, const int* in_sizes, int n_in,
                              void* d_out, int out_size, void* d_ws, size_t ws_size,
                              hipStream_t stream) {
    const int*   phw     = (const int*)d_in[0];
    const float* filters = (const float*)d_in[1];
    float*       out     = (float*)d_out;
    const int n = in_sizes[0] / 3;

    // Output is accumulated with atomics -> must start from zero every call
    // (harness poisons d_out with 0xAA). Async memset is graph-capture safe.
    hipMemsetAsync(out, 0, (size_t)H_ * W_ * sizeof(float), stream);

    const int segs = (n + SEG_LEN_ - 1) / SEG_LEN_;
    dim3 grid(W_ / TILE_, H_ / TILE_, segs);

    if (d_ws != nullptr && ws_size >= PAD_BYTES_) {
        // Build zero-bordered filter table in workspace (ws is poisoned each
        // iteration, so rebuild every launch), then render from it.
        float* pad = (float*)d_ws;
        build_pad_kernel<<<dim3(NPARTS_), dim3(256), 0, stream>>>(filters, pad);
        render_tile_kernel<true><<<grid, dim3(THREADS_), 0, stream>>>(phw, pad, out, n);
    } else {
        render_tile_kernel<false><<<grid, dim3(THREADS_), 0, stream>>>(phw, filters, out, n);
    }
}

// Round 2
// 82.598 us; speedup vs baseline: 1.0849x; 1.0849x over previous
//
#include <hip/hip_runtime.h>

// RenderingModel: scatter-add of 64x64 filters at N particle positions onto a
// 512x512 canvas (cropped). Gather formulation: each block owns a 32x32 output
// tile AND a 1024-particle segment (grid.z = 8). Phase 1 compacts hits into
// LDS; phase 2 accumulates in registers.
//
// R5 -> R6: R5 (zero-padded filter table, -50% phase-2 VALU) was NEUTRAL on
// the render kernel and paid +8 us for the build kernel -> phase-2 arithmetic
// is NOT the bottleneck; reverted. The one knob that has ever moved this
// kernel is global atomic count (R3's 4.2M was worse than R2/R4's 2M). The
// 2M device-scope fp32 atomics hit every output line from 8 blocks on 8
// NON-COHERENT XCDs -> serialized RMW at the coherence point, invisible to
// VALU arithmetic. R6 removes global atomics entirely:
//   - each segment-block stores its partial 32x32 tile with plain coalesced
//     stores into a private per-segment plane in d_ws (segs x 1MB, disjoint)
//   - a tiny reduce kernel sums the planes per pixel (float4, unrolled)
//   - hipMemsetAsync(out) deleted: reduce writes every output pixel.
// Fallback to the proven R4 atomic path if ws is ever too small.

#define H_  512
#define W_  512
#define FH_ 64
#define FW_ 64
#define TILE_ 32
#define THREADS_ 256
#define SEG_LEN_ 1024            // particles per segment; LDS list sized to this
#define PLANE_   (H_ * W_)       // floats per per-segment partial plane

__device__ __forceinline__ int clamp63(int v) {
    return min(max(v, 0), 63);   // -> v_med3_i32
}

template<bool PLANES>
__global__ __launch_bounds__(THREADS_, 8)
void render_tile_kernel(const int* __restrict__ phw,
                        const float* __restrict__ filters,
                        float* __restrict__ dst,   // planes base if PLANES, else out
                        int n) {
    __shared__ unsigned int s_list[SEG_LEN_];
    __shared__ int s_cnt;

    const int t   = threadIdx.x;
    const int tx0 = blockIdx.x * TILE_;
    const int ty0 = blockIdx.y * TILE_;
    const int k0  = blockIdx.z * SEG_LEN_;
    const int k1  = (k0 + SEG_LEN_ < n) ? (k0 + SEG_LEN_) : n;

    if (t == 0) s_cnt = 0;
    __syncthreads();

    // ---- Phase 1: bbox test + compaction of this segment into LDS ----
    for (int k = k0 + t; k < k1; k += THREADS_) {
        const int part = phw[k * 3 + 0];
        const int row  = phw[k * 3 + 1];
        const int col  = phw[k * 3 + 2];
        const bool hit =
            (row >= ty0 - (FH_ / 2 - 1)) && (row <= ty0 + TILE_ - 1 + FH_ / 2) &&
            (col >= tx0 - (FW_ / 2 - 1)) && (col <= tx0 + TILE_ - 1 + FW_ / 2);
        if (hit) {
            const int idx = atomicAdd(&s_cnt, 1);
            // pack: part(8b) | row(9b) | col(9b)
            s_list[idx] = ((unsigned)part << 18) | ((unsigned)row << 9) | (unsigned)col;
        }
    }
    __syncthreads();
    const int cnt = s_cnt;

    // ---- Phase 2: accumulate owned pixels in registers ----
    // Thread t owns pixels (x = tx0 + (t&31), y = ty0 + (t>>5) + 8q), q=0..3.
    const int xl    = t & 31;
    const int yb    = t >> 5;          // 0..7
    const int x     = tx0 + xl;
    const int ybase = ty0 + yb;

    float acc0 = 0.f, acc1 = 0.f, acc2 = 0.f, acc3 = 0.f;

    // One hit's contribution: branchless (clamped address, value select).
    // Entries are wave-uniform -> readfirstlane puts part/row/col in SGPRs;
    // loads are SGPR-base + small vector offset. Proven R4 body, unchanged.
    auto body = [&](unsigned v) {
        const int part = (int)__builtin_amdgcn_readfirstlane(v >> 18);
        const int row  = (int)__builtin_amdgcn_readfirstlane((v >> 9) & 511u);
        const int col  = (int)__builtin_amdgcn_readfirstlane(v & 511u);
        const float* __restrict__ f = filters + (part << 12);  // SGPR base

        const int  j   = x - col + (FW_ / 2);
        const int  jc  = clamp63(j);
        const bool jok = (unsigned)j < (unsigned)FW_;
        const int  i0  = ybase - row + (FH_ / 2);

        const int ia = i0;      const int ib = i0 + 8;
        const int ic = i0 + 16; const int id = i0 + 24;
        const float va = f[clamp63(ia) * FW_ + jc];   // unconditional loads,
        const float vb = f[clamp63(ib) * FW_ + jc];   // address always valid
        const float vc = f[clamp63(ic) * FW_ + jc];
        const float vd = f[clamp63(id) * FW_ + jc];
        acc0 += (jok && (unsigned)ia < (unsigned)FH_) ? va : 0.f;
        acc1 += (jok && (unsigned)ib < (unsigned)FH_) ? vb : 0.f;
        acc2 += (jok && (unsigned)ic < (unsigned)FH_) ? vc : 0.f;
        acc3 += (jok && (unsigned)id < (unsigned)FH_) ? vd : 0.f;
    };

    int k = 0;
    for (; k + 4 <= cnt; k += 4) {
        // 4 wave-uniform entries in one 16B LDS read (k%4==0 -> aligned)
        const uint4 vv = *(const uint4*)&s_list[k];
        body(vv.x); body(vv.y); body(vv.z); body(vv.w);
    }
    for (; k < cnt; ++k) body(s_list[k]);

    // ---- Epilogue ----
    if constexpr (PLANES) {
        // Private per-segment plane: disjoint plain stores, no RMW, no
        // cross-XCD line sharing. Coalesced: 32 consecutive x per half-wave.
        float* __restrict__ plane = dst + (size_t)blockIdx.z * PLANE_;
        plane[(ybase +  0) * W_ + x] = acc0;
        plane[(ybase +  8) * W_ + x] = acc1;
        plane[(ybase + 16) * W_ + x] = acc2;
        plane[(ybase + 24) * W_ + x] = acc3;
    } else {
        // Fallback: combine segments via device-scope fp32 atomics
        // (requires dst pre-zeroed).
        atomicAdd(&dst[(ybase +  0) * W_ + x], acc0);
        atomicAdd(&dst[(ybase +  8) * W_ + x], acc1);
        atomicAdd(&dst[(ybase + 16) * W_ + x], acc2);
        atomicAdd(&dst[(ybase + 24) * W_ + x], acc3);
    }
}

// Sum SEGS per-segment planes into out. 256 blocks x 256 threads x float4
// covers all 512*512 pixels exactly; every output pixel is written (so no
// output memset is needed). Fixed-order adds -> deterministic.
template<int SEGS>
__global__ __launch_bounds__(256)
void reduce_planes_fixed(const float* __restrict__ planes, float* __restrict__ out) {
    const int i = (blockIdx.x * 256 + threadIdx.x) * 4;
    float4 a = *(const float4*)&planes[i];
#pragma unroll
    for (int s = 1; s < SEGS; ++s) {
        const float4 b = *(const float4*)&planes[(size_t)s * PLANE_ + i];
        a.x += b.x; a.y += b.y; a.z += b.z; a.w += b.w;
    }
    *(float4*)&out[i] = a;
}

__global__ __launch_bounds__(256)
void reduce_planes_var(const float* __restrict__ planes, float* __restrict__ out,
                       int segs) {
    const int i = (blockIdx.x * 256 + threadIdx.x) * 4;
    float4 a = *(const float4*)&planes[i];
    for (int s = 1; s < segs; ++s) {
        const float4 b = *(const float4*)&planes[(size_t)s * PLANE_ + i];
        a.x += b.x; a.y += b.y; a.z += b.z; a.w += b.w;
    }
    *(float4*)&out[i] = a;
}

extern "C" void kernel_launch(void* const* d_in, const int* in_sizes, int n_in,
                              void* d_out, int out_size, void* d_ws, size_t ws_size,
                              hipStream_t stream) {
    const int*   phw     = (const int*)d_in[0];
    const float* filters = (const float*)d_in[1];
    float*       out     = (float*)d_out;
    const int n = in_sizes[0] / 3;

    if (n <= 0) {
        hipMemsetAsync(out, 0, (size_t)H_ * W_ * sizeof(float), stream);
        return;
    }

    const int segs = (n + SEG_LEN_ - 1) / SEG_LEN_;
    const size_t plane_bytes = (size_t)segs * PLANE_ * sizeof(float);
    dim3 grid(W_ / TILE_, H_ / TILE_, segs);

    if (d_ws != nullptr && ws_size >= plane_bytes) {
        // Atomic-free path: render partial planes into ws (fully overwritten
        // every call -> safe against ws re-poison), then reduce. reduce
        // writes every output pixel -> no memset of out needed.
        float* planes = (float*)d_ws;
        render_tile_kernel<true><<<grid, dim3(THREADS_), 0, stream>>>(
            phw, filters, planes, n);
        const int rblocks = PLANE_ / 4 / 256;   // 256
        if (segs == 8) {
            reduce_planes_fixed<8><<<dim3(rblocks), dim3(256), 0, stream>>>(planes, out);
        } else {
            reduce_planes_var<<<dim3(rblocks), dim3(256), 0, stream>>>(planes, out, segs);
        }
    } else {
        // Proven R4 fallback: zero out, render with device atomics.
        hipMemsetAsync(out, 0, (size_t)H_ * W_ * sizeof(float), stream);
        render_tile_kernel<false><<<grid, dim3(THREADS_), 0, stream>>>(
            phw, filters, out, n);
    }
}